// Round 11
// baseline (698.955 us; speedup 1.0000x reference)
//
#include <hip/hip_runtime.h>

#define N_TOK 32768
#define EMB_D 256
#define N_EMB 8192
#define TM 128          // tokens per score block
#define CHUNK 256       // codes per kc chunk
#define KS 32           // dims per dc slice
#define NKC (N_EMB / CHUNK)   // 32
#define NDC (EMB_D / KS)      // 8
#define NSLICE (NKC * NDC)    // 256

typedef __attribute__((ext_vector_type(8))) short short8;
typedef __attribute__((ext_vector_type(4))) float f32x4;
typedef unsigned short ushort_t;
typedef __attribute__((address_space(3))) unsigned int lds_uint;
typedef const __attribute__((address_space(1))) unsigned int gbl_uint;

// ---- LDS layout for vq_score (dynamic, 151552 B) ----
#define BUF_BYTES 73728
#define XA_OFF(p) ((p) * 8192)
#define EA_OFF(p) (24576 + (p) * 16384)
#define FIN_OFF   147456
#define SMEM_BYTES 151552

// ---- ws layout (bytes): xp[3]@0 (16 MB each), ep[3]@50331648 (4 MB each),
//      nh@62914560, cand@62947328 ----
#define WS_EP_BASE 50331648
#define WS_XPLANE  16777216
#define WS_EPLANE  4194304

__device__ __forceinline__ ushort_t rne_bf16(float f) {
    unsigned u = __float_as_uint(f);
    return (ushort_t)((u + 0x7FFFu + ((u >> 16) & 1u)) >> 16);
}
__device__ __forceinline__ float bf16_to_f32(ushort_t h) {
    return __uint_as_float(((unsigned)h) << 16);
}

// ---------------- split x into 3 bf16 planes --------------------------------
__global__ __launch_bounds__(256) void vq_split(const float* __restrict__ src,
                                                ushort_t* __restrict__ p0,
                                                ushort_t* __restrict__ p1,
                                                ushort_t* __restrict__ p2) {
    size_t i = (size_t)blockIdx.x * 256 + threadIdx.x;   // float4 index
    float4 v = *(const float4*)(src + i * 4);
    float vv[4] = {v.x, v.y, v.z, v.w};
    ushort_t h[4], m[4], l[4];
#pragma unroll
    for (int j = 0; j < 4; ++j) {
        ushort_t hh = rne_bf16(vv[j]);
        float r = vv[j] - bf16_to_f32(hh);      // exact (Sterbenz)
        ushort_t mm = rne_bf16(r);
        float r2 = r - bf16_to_f32(mm);         // exact
        h[j] = hh; m[j] = mm; l[j] = rne_bf16(r2);
    }
    *(ushort4*)(p0 + i * 4) = make_ushort4(h[0], h[1], h[2], h[3]);
    *(ushort4*)(p1 + i * 4) = make_ushort4(m[0], m[1], m[2], m[3]);
    *(ushort4*)(p2 + i * 4) = make_ushort4(l[0], l[1], l[2], l[3]);
}

// ---------------- split cb + fused norms + zero loss slot -------------------
// Each wave's 64 lanes cover exactly one codebook row (64 float4 = 256 f32),
// so the wave reduction of |v|^2 lands nh[row] for free.
__global__ __launch_bounds__(256) void vq_split_cb(const float* __restrict__ src,
                                                   ushort_t* __restrict__ p0,
                                                   ushort_t* __restrict__ p1,
                                                   ushort_t* __restrict__ p2,
                                                   float* __restrict__ nh,
                                                   float* __restrict__ out) {
    size_t i = (size_t)blockIdx.x * 256 + threadIdx.x;   // float4 index
    float4 v = *(const float4*)(src + i * 4);
    float vv[4] = {v.x, v.y, v.z, v.w};
    ushort_t h[4], m[4], l[4];
#pragma unroll
    for (int j = 0; j < 4; ++j) {
        ushort_t hh = rne_bf16(vv[j]);
        float r = vv[j] - bf16_to_f32(hh);
        ushort_t mm = rne_bf16(r);
        float r2 = r - bf16_to_f32(mm);
        h[j] = hh; m[j] = mm; l[j] = rne_bf16(r2);
    }
    *(ushort4*)(p0 + i * 4) = make_ushort4(h[0], h[1], h[2], h[3]);
    *(ushort4*)(p1 + i * 4) = make_ushort4(m[0], m[1], m[2], m[3]);
    *(ushort4*)(p2 + i * 4) = make_ushort4(l[0], l[1], l[2], l[3]);
    float ss = v.x * v.x + v.y * v.y + v.z * v.z + v.w * v.w;
#pragma unroll
    for (int off = 1; off < 64; off <<= 1) ss += __shfl_xor(ss, off);
    if ((threadIdx.x & 63) == 0) nh[i >> 6] = -0.5f * ss;
    if (blockIdx.x == 0 && threadIdx.x == 0) out[(size_t)N_TOK * EMB_D] = 0.0f;
}

// ---------------- MFMA 6-pass score + coarse argmax -------------------------
// maximize s'(t,k) = x_t.e_k - 0.5||e_k||^2  (equiv to min L2 distance)
// 2-phase global_load_lds pipeline; staging addresses advanced incrementally;
// passes outermost so same-accumulator MFMAs are 16 instructions apart.
__global__ __launch_bounds__(512, 2) void vq_score(const char* __restrict__ wsb,
                                                   const float* __restrict__ nh,
                                                   int* __restrict__ cand) {
    extern __shared__ char smem[];
    unsigned long long* fin = (unsigned long long*)(smem + FIN_OFF);

    const int tid = threadIdx.x;
    const int lane = tid & 63;
    const int wid = tid >> 6;
    const int wm = wid >> 2;     // 0..1: token half (64 rows)
    const int wn = wid & 3;      // 0..3: code quarter (64 codes)
    const int l15 = lane & 15;
    const int lg = lane >> 4;    // k-group 0..3
    const int row0 = blockIdx.x * TM;

    // Per-thread staging state: 32-bit ws offsets (slice 0) + constant LDS
    // offsets. LDS dst per wave is uniform + lane*16 (global_load_lds
    // contract); XOR row-swizzle is applied on the GLOBAL source side.
    int off[9];
    int ldso[9];
#pragma unroll
    for (int q = 0; q < 9; ++q) {
        int lin = tid + q * 512;
        if (q < 3) {
            int p = lin >> 9, rem = lin & 511;
            int row = rem >> 2, gs = rem & 3;
            int g = gs ^ ((row >> 1) & 3);
            off[q] = p * WS_XPLANE + (row0 + row) * 512 + g * 16;
            ldso[q] = XA_OFF(p) + row * 64 + gs * 16;
        } else {
            int l2 = lin - 1536;
            int p = l2 >> 10, rem = l2 & 1023;
            int row = rem >> 2, gs = rem & 3;
            int g = gs ^ ((row >> 1) & 3);
            off[q] = WS_EP_BASE + p * WS_EPLANE + row * 512 + g * 16;
            ldso[q] = EA_OFF(p) + row * 64 + gs * 16;
        }
    }
    auto STAGE = [&](int b) {
        char* base = smem + b * BUF_BYTES;
#pragma unroll
        for (int q = 0; q < 9; ++q)
            __builtin_amdgcn_global_load_lds((gbl_uint*)(wsb + (unsigned)off[q]),
                                             (lds_uint*)(base + ldso[q]), 16, 0, 0);
    };
    auto ADV = [&](int xadv, int eadv) {
#pragma unroll
        for (int q = 0; q < 9; ++q) off[q] += (q < 3) ? xadv : eadv;
    };

    float run[16];
    float tagf[16];
#pragma unroll
    for (int s = 0; s < 16; ++s) { run[s] = -3.0e38f; tagf[s] = 0.0f; }

    STAGE(0);
    ADV(64, 64);
    __syncthreads();          // drains vmcnt(0): buf0 ready
    int cur = 0;

    for (int kc = 0; kc < NKC; ++kc) {
        const int k0 = kc * CHUNK;
        f32x4 acc[4][4];
#pragma unroll
        for (int m = 0; m < 4; ++m)
#pragma unroll
            for (int n = 0; n < 4; ++n) acc[m][n] = (f32x4)0.0f;

        for (int dc = 0; dc < NDC; ++dc) {
            const int t = kc * NDC + dc;
            if (t + 1 < NSLICE) {
                STAGE(cur ^ 1);                     // prefetch next slice
                if (dc == 6) ADV(-448, 130624);     // kc boundary wrap
                else         ADV(64, 64);
            }

            char* base = smem + cur * BUF_BYTES;
            // load ALL fragments first: a[m][plane], b[n][plane]
            short8 a[4][3], b[4][3];
#pragma unroll
            for (int m = 0; m < 4; ++m) {
                int row = wm * 64 + m * 16 + l15;
                int gsw = lg ^ ((row >> 1) & 3);
#pragma unroll
                for (int p = 0; p < 3; ++p)
                    a[m][p] = *(const short8*)(base + XA_OFF(p) + row * 64 + gsw * 16);
            }
#pragma unroll
            for (int n = 0; n < 4; ++n) {
                int row = wn * 64 + n * 16 + l15;
                int gsw = lg ^ ((row >> 1) & 3);
#pragma unroll
                for (int p = 0; p < 3; ++p)
                    b[n][p] = *(const short8*)(base + EA_OFF(p) + row * 64 + gsw * 16);
            }
            // 6 passes outermost: per-acc contribution order is IDENTICAL to
            // the previous kernel (bitwise-same scores), but same-acc MFMAs
            // are now 16 apart -> no RAW-on-C stalls.
            constexpr int PA[6] = {0, 0, 1, 0, 1, 2};
            constexpr int PB[6] = {0, 1, 0, 2, 1, 0};
#pragma unroll
            for (int pp = 0; pp < 6; ++pp) {
                const int pa = PA[pp], pb = PB[pp];
#pragma unroll
                for (int n = 0; n < 4; ++n)
#pragma unroll
                    for (int m = 0; m < 4; ++m)
                        acc[m][n] = __builtin_amdgcn_mfma_f32_16x16x32_bf16(
                            a[m][pa], b[n][pb], acc[m][n], 0, 0, 0);
            }
            // one barrier per slice: s_waitcnt vmcnt(0) lgkmcnt(0) lands the
            // prefetch and protects buf[cur] from re-staging.
            __syncthreads();
            cur ^= 1;
        }
        // fold chunk into per-slot running max + kc tag
        float nhv[4];
#pragma unroll
        for (int n = 0; n < 4; ++n) nhv[n] = nh[k0 + wn * 64 + n * 16 + l15];
        float kcf = (float)kc;
#pragma unroll
        for (int m = 0; m < 4; ++m)
#pragma unroll
            for (int r = 0; r < 4; ++r) {
                float s = acc[m][0][r] + nhv[0];
                s = fmaxf(s, acc[m][1][r] + nhv[1]);
                s = fmaxf(s, acc[m][2][r] + nhv[2]);
                s = fmaxf(s, acc[m][3][r] + nhv[3]);
                int slot = m * 4 + r;
                bool upd = s > run[slot];            // strict >: first chunk wins ties
                run[slot] = upd ? s : run[slot];
                tagf[slot] = upd ? kcf : tagf[slot];
            }
    }

    // final: per-slot cross-lane (16-group) argmax with packed (score, meta)
#pragma unroll
    for (int s = 0; s < 16; ++s) {
        unsigned u = __float_as_uint(run[s]);
        unsigned ord = (u & 0x80000000u) ? ~u : (u | 0x80000000u);  // monotone map
        unsigned tag = (unsigned)tagf[s];
        unsigned meta = 0x1FFu ^ ((tag << 4) | (unsigned)l15);      // larger = smaller code
        unsigned long long key = ((unsigned long long)ord << 32) | meta;
#pragma unroll
        for (int off2 = 1; off2 <= 8; off2 <<= 1) {
            unsigned long long o = __shfl_xor(key, off2);
            if (o > key) key = o;
        }
        if (l15 == s) {
            int m = s >> 2, r = s & 3;
            int token = wm * 64 + m * 16 + lg * 4 + r;
            fin[token * 4 + wn] = key;
        }
    }
    __syncthreads();
    if (tid < TM) {
        unsigned long long best = fin[tid * 4];
        int bwn = 0;
#pragma unroll
        for (int w = 1; w < 4; ++w) {
            unsigned long long v = fin[tid * 4 + w];
            if (v > best) { best = v; bwn = w; }    // strict >: smaller wn (code) on tie
        }
        unsigned raw = 0x1FFu ^ ((unsigned)best & 0x1FFu);
        int tag = (int)(raw >> 4), ln4 = (int)(raw & 15u);
        cand[row0 + tid] = tag * CHUNK + bwn * 64 + ln4;   // + nf*16 resolved in finish
    }
}

// ---------------- fused resolve (4 candidates, f32) + gather + loss ---------
__global__ __launch_bounds__(256) void vq_finish(const float* __restrict__ x,
                                                 const float* __restrict__ cb,
                                                 const float* __restrict__ nh,
                                                 const int* __restrict__ cand,
                                                 float* __restrict__ out) {
    __shared__ int sidx[64];
    __shared__ float red[4];
    int tid = threadIdx.x, w = tid >> 6, lane = tid & 63;
    int t0 = blockIdx.x * 64;

    // phase 1: each wave resolves 16 tokens (full f32 re-score of 4 candidates)
    for (int i = 0; i < 16; ++i) {
        int t = t0 + w * 16 + i;
        int base = cand[t];
        float4 xv = *(const float4*)(x + (size_t)t * EMB_D + lane * 4);
        float best = -3.0e38f;
        int bc = base;
#pragma unroll
        for (int nf = 0; nf < 4; ++nf) {
            float4 ev = *(const float4*)(cb + (size_t)(base + nf * 16) * EMB_D + lane * 4);
            float d = xv.x * ev.x + xv.y * ev.y + xv.z * ev.z + xv.w * ev.w;
#pragma unroll
            for (int off = 1; off < 64; off <<= 1) d += __shfl_xor(d, off);
            d += nh[base + nf * 16];
            if (d > best) { best = d; bc = base + nf * 16; }  // strict >: smaller code on tie
        }
        if (lane == 0) sidx[w * 16 + i] = bc;
    }
    __syncthreads();

    // phase 2: gather + loss (tid = dim)
    float lsum = 0.f;
    for (int tt = 0; tt < 64; ++tt) {
        int t = t0 + tt;
        int k = sidx[tt];
        float q = cb[(size_t)k * EMB_D + tid];
        float xv = x[(size_t)t * EMB_D + tid];
        out[(size_t)t * EMB_D + tid] = q;
        float dq = q - xv;
        lsum = fmaf(dq, dq, lsum);
    }
#pragma unroll
    for (int off = 1; off < 64; off <<= 1) lsum += __shfl_xor(lsum, off);
    if (lane == 0) red[w] = lsum;
    __syncthreads();
    if (tid == 0) {
        float ssum = red[0] + red[1] + red[2] + red[3];
        atomicAdd(out + (size_t)N_TOK * EMB_D,
                  ssum * (1.25f / (float)((size_t)N_TOK * EMB_D)));
    }
}

extern "C" void kernel_launch(void* const* d_in, const int* in_sizes, int n_in,
                              void* d_out, int out_size, void* d_ws, size_t ws_size,
                              hipStream_t stream) {
    const float* x = (const float*)d_in[0];
    const float* cb = (const float*)d_in[1];
    float* out = (float*)d_out;

    char* ws = (char*)d_ws;
    ushort_t* xp0 = (ushort_t*)(ws);
    ushort_t* xp1 = (ushort_t*)(ws + WS_XPLANE);
    ushort_t* xp2 = (ushort_t*)(ws + 2 * WS_XPLANE);
    ushort_t* ep0 = (ushort_t*)(ws + WS_EP_BASE);
    ushort_t* ep1 = (ushort_t*)(ws + WS_EP_BASE + WS_EPLANE);
    ushort_t* ep2 = (ushort_t*)(ws + WS_EP_BASE + 2 * WS_EPLANE);
    float* nh     = (float*)(ws + 62914560);
    int* cand     = (int*)(ws + 62947328);

    vq_split<<<(N_TOK * EMB_D / 4) / 256, 256, 0, stream>>>(x, xp0, xp1, xp2);
    vq_split_cb<<<(N_EMB * EMB_D / 4) / 256, 256, 0, stream>>>(cb, ep0, ep1, ep2,
                                                               nh, out);

    hipFuncSetAttribute((const void*)vq_score,
                        hipFuncAttributeMaxDynamicSharedMemorySize, SMEM_BYTES);
    vq_score<<<N_TOK / TM, 512, SMEM_BYTES, stream>>>(ws, nh, cand);
    vq_finish<<<N_TOK / 64, 256, 0, stream>>>(x, cb, nh, cand, out);
}